// Round 1
// baseline (370.118 us; speedup 1.0000x reference)
//
#include <hip/hip_runtime.h>
#include <hip/hip_bf16.h>
#include <math.h>

#define T_NODES 8192
#define BGRAPHS 16
#define CDIM 128
#define HEADS 4
#define DHEAD 32
#define KNN 16

// ---------------------------------------------------------------------------
// Kernel 1: segment counts/starts from sorted batch ids
// ---------------------------------------------------------------------------
__global__ __launch_bounds__(256) void k_counts(const int* __restrict__ batch,
                                                int* __restrict__ starts,
                                                int* __restrict__ counts) {
    __shared__ int cnt[BGRAPHS];
    int tid = threadIdx.x;
    if (tid < BGRAPHS) cnt[tid] = 0;
    __syncthreads();
    for (int i = tid; i < T_NODES; i += 256) {
        atomicAdd(&cnt[batch[i]], 1);
    }
    __syncthreads();
    if (tid == 0) {
        int s = 0;
        for (int b = 0; b < BGRAPHS; ++b) {
            starts[b] = s;
            counts[b] = cnt[b];
            s += cnt[b];
        }
    }
}

// ---------------------------------------------------------------------------
// Kernel 2: node embedding f0 = x @ emb_W + emb_b   [T,128]
// ---------------------------------------------------------------------------
__global__ __launch_bounds__(256) void k_embed(const float* __restrict__ x,
                                               const float* __restrict__ embW,
                                               const float* __restrict__ embb,
                                               float* __restrict__ f0) {
    int gid = blockIdx.x * 256 + threadIdx.x;
    int t = gid >> 7;
    int c = gid & 127;
    float acc = embb[c];
#pragma unroll
    for (int i = 0; i < 11; ++i) {
        acc += x[t * 11 + i] * embW[i * CDIM + c];
    }
    f0[t * CDIM + c] = acc;
}

// ---------------------------------------------------------------------------
// Kernel 3: kNN. One wave (64 lanes) per node. Each lane holds 16 candidate
// slots (covers up to 1024 nodes/graph). 16 rounds of argmin-reduce.
// Tie-break: smaller index wins (matches jax.lax.top_k).
// ---------------------------------------------------------------------------
__global__ __launch_bounds__(256) void k_knn(const float* __restrict__ pos,
                                             const int* __restrict__ batch,
                                             const int* __restrict__ starts,
                                             const int* __restrict__ counts,
                                             int* __restrict__ nbr,
                                             float* __restrict__ dist,
                                             float* __restrict__ dirv) {
    int wave = threadIdx.x >> 6;
    int lane = threadIdx.x & 63;
    int t = blockIdx.x * 4 + wave;
    if (t >= T_NODES) return;

    int b = batch[t];
    int s = starts[b];
    int n = counts[b];

    float px = pos[t * 3 + 0];
    float py = pos[t * 3 + 1];
    float pz = pos[t * 3 + 2];

    float d2s[16];
#pragma unroll
    for (int sl = 0; sl < 16; ++sl) {
        int j = lane + sl * 64;
        float d2 = 1e30f;
        if (j < n) {
            int jj = s + j;
            float dx = px - pos[jj * 3 + 0];
            float dy = py - pos[jj * 3 + 1];
            float dz = pz - pos[jj * 3 + 2];
            d2 = dx * dx + dy * dy + dz * dz;
        }
        d2s[sl] = d2;
    }

    float resd = 1e30f;
    int resj = -1;

#pragma unroll
    for (int r = 0; r < KNN; ++r) {
        // local argmin over my 16 slots (static indices)
        float bd = 1e30f;
        int bj = 0x7fffffff;
#pragma unroll
        for (int sl = 0; sl < 16; ++sl) {
            int j = lane + sl * 64;
            float d2 = d2s[sl];
            bool take = (d2 < bd) || (d2 == bd && j < bj);
            bd = take ? d2 : bd;
            bj = take ? j : bj;
        }
        // wave argmin reduce (lexicographic (d2, j))
#pragma unroll
        for (int off = 32; off >= 1; off >>= 1) {
            float od = __shfl_xor(bd, off);
            int oj = __shfl_xor(bj, off);
            bool take = (od < bd) || (od == bd && oj < bj);
            bd = take ? od : bd;
            bj = take ? oj : bj;
        }
        // invalidate winner (owning lane only; static slot compare)
#pragma unroll
        for (int sl = 0; sl < 16; ++sl) {
            int j = lane + sl * 64;
            if (j == bj) d2s[sl] = 1e30f;
        }
        if (lane == r) { resd = bd; resj = bj; }
    }

    if (lane < KNN) {
        bool valid = (resd < 1e29f);
        int jf = valid ? (s + resj) : -1;
        nbr[t * KNN + lane] = jf;
        float dd = sqrtf(resd + 1e-6f);
        dist[t * KNN + lane] = dd;
        float dx = 0.f, dy = 0.f, dz = 0.f;
        if (valid) {
            float inv = 1.f / dd;
            dx = (px - pos[jf * 3 + 0]) * inv;
            dy = (py - pos[jf * 3 + 1]) * inv;
            dz = (pz - pos[jf * 3 + 2]) * inv;
        }
        dirv[(t * KNN + lane) * 3 + 0] = dx;
        dirv[(t * KNN + lane) * 3 + 1] = dy;
        dirv[(t * KNN + lane) * 3 + 2] = dz;
    }
}

// ---------------------------------------------------------------------------
// Kernel 4: fused QKV projection. qkvv[t, 0:512] = f0[t,:] @ [Wq|Wk|Wv0|Wv1]
// 16 nodes per block, 256 threads. Thread owns 2 output columns x 16 nodes.
// ---------------------------------------------------------------------------
__global__ __launch_bounds__(256) void k_qkv(const float* __restrict__ f0,
                                             const float* __restrict__ Wq,
                                             const float* __restrict__ Wk,
                                             const float* __restrict__ Wv0,
                                             const float* __restrict__ Wv1,
                                             float* __restrict__ qkvv) {
    __shared__ float sf[16][CDIM];
    int t0 = blockIdx.x * 16;
    int tid = threadIdx.x;
    for (int i = tid; i < 16 * CDIM; i += 256) {
        sf[i >> 7][i & 127] = f0[(t0 + (i >> 7)) * CDIM + (i & 127)];
    }
    __syncthreads();

    const float* W1 = (tid < 128) ? Wq : Wk;    // wave-uniform
    const float* W2 = (tid < 128) ? Wv0 : Wv1;  // wave-uniform
    int col = tid & 127;

    float acc1[16], acc2[16];
#pragma unroll
    for (int nn = 0; nn < 16; ++nn) { acc1[nn] = 0.f; acc2[nn] = 0.f; }

    for (int c0 = 0; c0 < CDIM; c0 += 8) {
        float w1[8], w2[8];
#pragma unroll
        for (int cc = 0; cc < 8; ++cc) {
            w1[cc] = W1[(c0 + cc) * CDIM + col];
            w2[cc] = W2[(c0 + cc) * CDIM + col];
        }
#pragma unroll
        for (int nn = 0; nn < 16; ++nn) {
            float4 fa = *(const float4*)&sf[nn][c0];
            float4 fb = *(const float4*)&sf[nn][c0 + 4];
            acc1[nn] += fa.x * w1[0] + fa.y * w1[1] + fa.z * w1[2] + fa.w * w1[3]
                      + fb.x * w1[4] + fb.y * w1[5] + fb.z * w1[6] + fb.w * w1[7];
            acc2[nn] += fa.x * w2[0] + fa.y * w2[1] + fa.z * w2[2] + fa.w * w2[3]
                      + fb.x * w2[4] + fb.y * w2[5] + fb.z * w2[6] + fb.w * w2[7];
        }
    }
#pragma unroll
    for (int nn = 0; nn < 16; ++nn) {
        qkvv[(size_t)(t0 + nn) * 512 + tid] = acc1[nn];
        qkvv[(size_t)(t0 + nn) * 512 + 256 + tid] = acc2[nn];
    }
}

// ---------------------------------------------------------------------------
// Kernel 5: kNN attention. One block (128 threads = channels) per node.
// out0 [T,128]; out1 planar [3][T,128].
// ---------------------------------------------------------------------------
__global__ __launch_bounds__(128) void k_attn(const float* __restrict__ qkvv,
                                              const int* __restrict__ nbr,
                                              const float* __restrict__ dist,
                                              const float* __restrict__ dirv,
                                              const float* __restrict__ dist_scale,
                                              float* __restrict__ out0,
                                              float* __restrict__ out1) {
    int t = blockIdx.x;
    int c = threadIdx.x;  // 0..127
    int h = c >> 5;

    float q = qkvv[(size_t)t * 512 + c];
    float xs = dist_scale[h];
    float sp = (xs > 20.f) ? xs : log1pf(expf(xs));  // softplus

    int js[KNN];
    float lg[KNN];
#pragma unroll
    for (int k = 0; k < KNN; ++k) {
        int j = nbr[t * KNN + k];
        js[k] = j;
        float kv = (j >= 0) ? qkvv[(size_t)j * 512 + 128 + c] : 0.f;
        float p = q * kv;
        p += __shfl_xor(p, 16);
        p += __shfl_xor(p, 8);
        p += __shfl_xor(p, 4);
        p += __shfl_xor(p, 2);
        p += __shfl_xor(p, 1);
        float l = -1e30f;
        if (j >= 0) l = p * 0.17677669529663687f - sp * dist[t * KNN + k];
        lg[k] = l;
    }

    float m = lg[0];
#pragma unroll
    for (int k = 1; k < KNN; ++k) m = fmaxf(m, lg[k]);
    float ssum = 0.f;
    float at[KNN];
#pragma unroll
    for (int k = 0; k < KNN; ++k) {
        float e = expf(lg[k] - m);
        at[k] = e;
        ssum += e;
    }
    float rs = 1.f / ssum;

    float o0 = 0.f, o1x = 0.f, o1y = 0.f, o1z = 0.f;
#pragma unroll
    for (int k = 0; k < KNN; ++k) {
        int j = js[k];
        if (j >= 0) {
            float a = at[k] * rs;
            float v0 = qkvv[(size_t)j * 512 + 256 + c];
            float v1 = qkvv[(size_t)j * 512 + 384 + c];
            o0 += a * v0;
            float av1 = a * v1;
            o1x += av1 * dirv[(t * KNN + k) * 3 + 0];
            o1y += av1 * dirv[(t * KNN + k) * 3 + 1];
            o1z += av1 * dirv[(t * KNN + k) * 3 + 2];
        }
    }
    out0[(size_t)t * CDIM + c] = o0;
    out1[0 * (size_t)T_NODES * CDIM + (size_t)t * CDIM + c] = o1x;
    out1[1 * (size_t)T_NODES * CDIM + (size_t)t * CDIM + c] = o1y;
    out1[2 * (size_t)T_NODES * CDIM + (size_t)t * CDIM + c] = o1z;
}

// ---------------------------------------------------------------------------
// Kernel 6: f1 = out1 @ Wo1 (per xyz), inv = ||f1||, f0_out = f0 + out0@Wo0 + inv@Wg
// 16 nodes per block, 256 threads (2 halves x 128 channels).
// ---------------------------------------------------------------------------
__global__ __launch_bounds__(256) void k_mix(const float* __restrict__ f0,
                                             const float* __restrict__ out0,
                                             const float* __restrict__ out1,
                                             const float* __restrict__ Wo1,
                                             const float* __restrict__ Wo0,
                                             const float* __restrict__ Wg,
                                             float* __restrict__ f0out) {
    __shared__ float sinv[16][CDIM];
    int t0 = blockIdx.x * 16;
    int d = threadIdx.x & 127;
    int half = threadIdx.x >> 7;  // 0 or 1

    // Phase 1: f1 / inv for nodes nn = half + 2*i
    float a0[8], a1[8], a2[8];
#pragma unroll
    for (int i = 0; i < 8; ++i) { a0[i] = 0.f; a1[i] = 0.f; a2[i] = 0.f; }

    for (int c0 = 0; c0 < CDIM; c0 += 8) {
        float w[8];
#pragma unroll
        for (int cc = 0; cc < 8; ++cc) w[cc] = Wo1[(c0 + cc) * CDIM + d];
#pragma unroll
        for (int i = 0; i < 8; ++i) {
            int t = t0 + half + 2 * i;
#pragma unroll
            for (int cc = 0; cc < 8; ++cc) {
                float wv = w[cc];
                a0[i] += out1[0 * (size_t)T_NODES * CDIM + (size_t)t * CDIM + c0 + cc] * wv;
                a1[i] += out1[1 * (size_t)T_NODES * CDIM + (size_t)t * CDIM + c0 + cc] * wv;
                a2[i] += out1[2 * (size_t)T_NODES * CDIM + (size_t)t * CDIM + c0 + cc] * wv;
            }
        }
    }
#pragma unroll
    for (int i = 0; i < 8; ++i) {
        int nn = half + 2 * i;
        sinv[nn][d] = sqrtf(a0[i] * a0[i] + a1[i] * a1[i] + a2[i] * a2[i] + 1e-6f);
    }
    __syncthreads();

    // Phase 2: f0_out = f0 + out0 @ Wo0 + inv @ Wg
    float r[8];
#pragma unroll
    for (int i = 0; i < 8; ++i) {
        int t = t0 + half + 2 * i;
        r[i] = f0[(size_t)t * CDIM + d];
    }
    for (int c0 = 0; c0 < CDIM; c0 += 8) {
        float wo[8], wg[8];
#pragma unroll
        for (int cc = 0; cc < 8; ++cc) {
            wo[cc] = Wo0[(c0 + cc) * CDIM + d];
            wg[cc] = Wg[(c0 + cc) * CDIM + d];
        }
#pragma unroll
        for (int i = 0; i < 8; ++i) {
            int nn = half + 2 * i;
            int t = t0 + nn;
#pragma unroll
            for (int cc = 0; cc < 8; ++cc) {
                r[i] += out0[(size_t)t * CDIM + c0 + cc] * wo[cc]
                      + sinv[nn][c0 + cc] * wg[cc];
            }
        }
    }
#pragma unroll
    for (int i = 0; i < 8; ++i) {
        int t = t0 + half + 2 * i;
        f0out[(size_t)t * CDIM + d] = r[i];
    }
}

// ---------------------------------------------------------------------------
// Kernel 7: masked mean pool per graph + linear head -> out [B,19]
// ---------------------------------------------------------------------------
__global__ __launch_bounds__(128) void k_pool(const float* __restrict__ f0out,
                                              const int* __restrict__ starts,
                                              const int* __restrict__ counts,
                                              const float* __restrict__ headW,
                                              const float* __restrict__ headb,
                                              float* __restrict__ out) {
    int b = blockIdx.x;
    int c = threadIdx.x;  // 0..127
    int s = starts[b];
    int n = counts[b];
    float acc = 0.f;
    for (int i = 0; i < n; ++i) acc += f0out[(size_t)(s + i) * CDIM + c];
    float denom = fmaxf((float)n, 1.f);
    __shared__ float pooled[CDIM];
    pooled[c] = acc / denom;
    __syncthreads();
    if (c < 19) {
        float rr = headb[c];
        for (int cc = 0; cc < CDIM; ++cc) rr += pooled[cc] * headW[cc * 19 + c];
        out[b * 19 + c] = rr;
    }
}

// ---------------------------------------------------------------------------
extern "C" void kernel_launch(void* const* d_in, const int* in_sizes, int n_in,
                              void* d_out, int out_size, void* d_ws, size_t ws_size,
                              hipStream_t stream) {
    const float* x    = (const float*)d_in[0];   // [T,11]
    const float* pos  = (const float*)d_in[1];   // [T,3]
    const int* batch  = (const int*)d_in[2];     // [T]
    const float* embW = (const float*)d_in[3];   // [11,128]
    const float* embb = (const float*)d_in[4];   // [128]
    const float* Wq   = (const float*)d_in[5];
    const float* Wk   = (const float*)d_in[6];
    const float* Wv0  = (const float*)d_in[7];
    const float* Wv1  = (const float*)d_in[8];
    const float* Wo0  = (const float*)d_in[9];
    const float* Wo1  = (const float*)d_in[10];
    const float* Wg   = (const float*)d_in[11];
    const float* dist_scale = (const float*)d_in[12];  // [4]
    const float* headW = (const float*)d_in[13];       // [128,19]
    const float* headb = (const float*)d_in[14];       // [19]
    float* out = (float*)d_out;                        // [16,19]

    char* w = (char*)d_ws;
    int* counts = (int*)w;
    int* starts = (int*)(w + 64);
    float* f0   = (float*)(w + 256);
    float* qkvv = f0 + (size_t)T_NODES * CDIM;
    int* nbr    = (int*)(qkvv + (size_t)T_NODES * 512);
    float* dist = (float*)(nbr + (size_t)T_NODES * KNN);
    float* dirv = dist + (size_t)T_NODES * KNN;
    float* out0 = dirv + (size_t)T_NODES * KNN * 3;
    float* out1 = out0 + (size_t)T_NODES * CDIM;
    float* f0out = out1 + (size_t)T_NODES * CDIM * 3;

    k_counts<<<1, 256, 0, stream>>>(batch, starts, counts);
    k_embed<<<(T_NODES * CDIM) / 256, 256, 0, stream>>>(x, embW, embb, f0);
    k_knn<<<T_NODES / 4, 256, 0, stream>>>(pos, batch, starts, counts, nbr, dist, dirv);
    k_qkv<<<T_NODES / 16, 256, 0, stream>>>(f0, Wq, Wk, Wv0, Wv1, qkvv);
    k_attn<<<T_NODES, 128, 0, stream>>>(qkvv, nbr, dist, dirv, dist_scale, out0, out1);
    k_mix<<<T_NODES / 16, 256, 0, stream>>>(f0, out0, out1, Wo1, Wo0, Wg, f0out);
    k_pool<<<BGRAPHS, 128, 0, stream>>>(f0out, starts, counts, headW, headb, out);
}

// Round 3
// 251.962 us; speedup vs baseline: 1.4689x; 1.4689x over previous
//
#include <hip/hip_runtime.h>
#include <hip/hip_bf16.h>
#include <math.h>

#define T_NODES 8192
#define BGRAPHS 16
#define CDIM 128
#define HEADS 4
#define DHEAD 32
#define KNN 16

// ---------------------------------------------------------------------------
// Kernel 1: segment counts/starts from sorted batch ids
// ---------------------------------------------------------------------------
__global__ __launch_bounds__(256) void k_counts(const int* __restrict__ batch,
                                                int* __restrict__ starts,
                                                int* __restrict__ counts) {
    __shared__ int cnt[BGRAPHS];
    int tid = threadIdx.x;
    if (tid < BGRAPHS) cnt[tid] = 0;
    __syncthreads();
    for (int i = tid; i < T_NODES; i += 256) {
        atomicAdd(&cnt[batch[i]], 1);
    }
    __syncthreads();
    if (tid == 0) {
        int s = 0;
        for (int b = 0; b < BGRAPHS; ++b) {
            starts[b] = s;
            counts[b] = cnt[b];
            s += cnt[b];
        }
    }
}

// ---------------------------------------------------------------------------
// Kernel 2: node embedding f0 = x @ emb_W + emb_b   [T,128]
// ---------------------------------------------------------------------------
__global__ __launch_bounds__(256) void k_embed(const float* __restrict__ x,
                                               const float* __restrict__ embW,
                                               const float* __restrict__ embb,
                                               float* __restrict__ f0) {
    int gid = blockIdx.x * 256 + threadIdx.x;
    int t = gid >> 7;
    int c = gid & 127;
    float acc = embb[c];
#pragma unroll
    for (int i = 0; i < 11; ++i) {
        acc += x[t * 11 + i] * embW[i * CDIM + c];
    }
    f0[t * CDIM + c] = acc;
}

// ---------------------------------------------------------------------------
// Kernel 3: kNN. One wave (64 lanes) per node. Each lane holds 16 candidate
// slots (covers up to 1024 nodes/graph). 16 rounds of argmin-reduce.
// Tie-break: smaller index wins (matches jax.lax.top_k).
// ---------------------------------------------------------------------------
__global__ __launch_bounds__(256) void k_knn(const float* __restrict__ pos,
                                             const int* __restrict__ batch,
                                             const int* __restrict__ starts,
                                             const int* __restrict__ counts,
                                             int* __restrict__ nbr,
                                             float* __restrict__ dist,
                                             float* __restrict__ dirv) {
    int wave = threadIdx.x >> 6;
    int lane = threadIdx.x & 63;
    int t = blockIdx.x * 4 + wave;
    if (t >= T_NODES) return;

    int b = batch[t];
    int s = starts[b];
    int n = counts[b];

    float px = pos[t * 3 + 0];
    float py = pos[t * 3 + 1];
    float pz = pos[t * 3 + 2];

    float d2s[16];
#pragma unroll
    for (int sl = 0; sl < 16; ++sl) {
        int j = lane + sl * 64;
        float d2 = 1e30f;
        if (j < n) {
            int jj = s + j;
            float dx = px - pos[jj * 3 + 0];
            float dy = py - pos[jj * 3 + 1];
            float dz = pz - pos[jj * 3 + 2];
            d2 = dx * dx + dy * dy + dz * dz;
        }
        d2s[sl] = d2;
    }

    float resd = 1e30f;
    int resj = -1;

#pragma unroll
    for (int r = 0; r < KNN; ++r) {
        // local argmin over my 16 slots (static indices)
        float bd = 1e30f;
        int bj = 0x7fffffff;
#pragma unroll
        for (int sl = 0; sl < 16; ++sl) {
            int j = lane + sl * 64;
            float d2 = d2s[sl];
            bool take = (d2 < bd) || (d2 == bd && j < bj);
            bd = take ? d2 : bd;
            bj = take ? j : bj;
        }
        // wave argmin reduce (lexicographic (d2, j))
#pragma unroll
        for (int off = 32; off >= 1; off >>= 1) {
            float od = __shfl_xor(bd, off);
            int oj = __shfl_xor(bj, off);
            bool take = (od < bd) || (od == bd && oj < bj);
            bd = take ? od : bd;
            bj = take ? oj : bj;
        }
        // invalidate winner (owning lane only; static slot compare)
#pragma unroll
        for (int sl = 0; sl < 16; ++sl) {
            int j = lane + sl * 64;
            if (j == bj) d2s[sl] = 1e30f;
        }
        if (lane == r) { resd = bd; resj = bj; }
    }

    if (lane < KNN) {
        bool valid = (resd < 1e29f);
        int jf = valid ? (s + resj) : -1;
        nbr[t * KNN + lane] = jf;
        float dd = sqrtf(resd + 1e-6f);
        dist[t * KNN + lane] = dd;
        float dx = 0.f, dy = 0.f, dz = 0.f;
        if (valid) {
            float inv = 1.f / dd;
            dx = (px - pos[jf * 3 + 0]) * inv;
            dy = (py - pos[jf * 3 + 1]) * inv;
            dz = (pz - pos[jf * 3 + 2]) * inv;
        }
        dirv[(t * KNN + lane) * 3 + 0] = dx;
        dirv[(t * KNN + lane) * 3 + 1] = dy;
        dirv[(t * KNN + lane) * 3 + 2] = dz;
    }
}

// ---------------------------------------------------------------------------
// Kernel 4: fused QKV projection. qkvv[t, 0:512] = f0[t,:] @ [Wq|Wk|Wv0|Wv1]
// 16 nodes per block, 256 threads. Thread owns 2 output columns x 16 nodes.
// ---------------------------------------------------------------------------
__global__ __launch_bounds__(256) void k_qkv(const float* __restrict__ f0,
                                             const float* __restrict__ Wq,
                                             const float* __restrict__ Wk,
                                             const float* __restrict__ Wv0,
                                             const float* __restrict__ Wv1,
                                             float* __restrict__ qkvv) {
    __shared__ float sf[16][CDIM];
    int t0 = blockIdx.x * 16;
    int tid = threadIdx.x;
    for (int i = tid; i < 16 * CDIM; i += 256) {
        sf[i >> 7][i & 127] = f0[(t0 + (i >> 7)) * CDIM + (i & 127)];
    }
    __syncthreads();

    const float* W1 = (tid < 128) ? Wq : Wk;    // wave-uniform
    const float* W2 = (tid < 128) ? Wv0 : Wv1;  // wave-uniform
    int col = tid & 127;

    float acc1[16], acc2[16];
#pragma unroll
    for (int nn = 0; nn < 16; ++nn) { acc1[nn] = 0.f; acc2[nn] = 0.f; }

    for (int c0 = 0; c0 < CDIM; c0 += 8) {
        float w1[8], w2[8];
#pragma unroll
        for (int cc = 0; cc < 8; ++cc) {
            w1[cc] = W1[(c0 + cc) * CDIM + col];
            w2[cc] = W2[(c0 + cc) * CDIM + col];
        }
#pragma unroll
        for (int nn = 0; nn < 16; ++nn) {
            float4 fa = *(const float4*)&sf[nn][c0];
            float4 fb = *(const float4*)&sf[nn][c0 + 4];
            acc1[nn] += fa.x * w1[0] + fa.y * w1[1] + fa.z * w1[2] + fa.w * w1[3]
                      + fb.x * w1[4] + fb.y * w1[5] + fb.z * w1[6] + fb.w * w1[7];
            acc2[nn] += fa.x * w2[0] + fa.y * w2[1] + fa.z * w2[2] + fa.w * w2[3]
                      + fb.x * w2[4] + fb.y * w2[5] + fb.z * w2[6] + fb.w * w2[7];
        }
    }
#pragma unroll
    for (int nn = 0; nn < 16; ++nn) {
        qkvv[(size_t)(t0 + nn) * 512 + tid] = acc1[nn];
        qkvv[(size_t)(t0 + nn) * 512 + 256 + tid] = acc2[nn];
    }
}

// ---------------------------------------------------------------------------
// Kernel 5: kNN attention. One block (128 threads = channels) per node.
// out0 [T,128]; out1 planar [3][T,128].
// ---------------------------------------------------------------------------
__global__ __launch_bounds__(128) void k_attn(const float* __restrict__ qkvv,
                                              const int* __restrict__ nbr,
                                              const float* __restrict__ dist,
                                              const float* __restrict__ dirv,
                                              const float* __restrict__ dist_scale,
                                              float* __restrict__ out0,
                                              float* __restrict__ out1) {
    int t = blockIdx.x;
    int c = threadIdx.x;  // 0..127
    int h = c >> 5;

    float q = qkvv[(size_t)t * 512 + c];
    float xs = dist_scale[h];
    float sp = (xs > 20.f) ? xs : log1pf(expf(xs));  // softplus

    int js[KNN];
    float lg[KNN];
#pragma unroll
    for (int k = 0; k < KNN; ++k) {
        int j = nbr[t * KNN + k];
        js[k] = j;
        float kv = (j >= 0) ? qkvv[(size_t)j * 512 + 128 + c] : 0.f;
        float p = q * kv;
        p += __shfl_xor(p, 16);
        p += __shfl_xor(p, 8);
        p += __shfl_xor(p, 4);
        p += __shfl_xor(p, 2);
        p += __shfl_xor(p, 1);
        float l = -1e30f;
        if (j >= 0) l = p * 0.17677669529663687f - sp * dist[t * KNN + k];
        lg[k] = l;
    }

    float m = lg[0];
#pragma unroll
    for (int k = 1; k < KNN; ++k) m = fmaxf(m, lg[k]);
    float ssum = 0.f;
    float at[KNN];
#pragma unroll
    for (int k = 0; k < KNN; ++k) {
        float e = expf(lg[k] - m);
        at[k] = e;
        ssum += e;
    }
    float rs = 1.f / ssum;

    float o0 = 0.f, o1x = 0.f, o1y = 0.f, o1z = 0.f;
#pragma unroll
    for (int k = 0; k < KNN; ++k) {
        int j = js[k];
        if (j >= 0) {
            float a = at[k] * rs;
            float v0 = qkvv[(size_t)j * 512 + 256 + c];
            float v1 = qkvv[(size_t)j * 512 + 384 + c];
            o0 += a * v0;
            float av1 = a * v1;
            o1x += av1 * dirv[(t * KNN + k) * 3 + 0];
            o1y += av1 * dirv[(t * KNN + k) * 3 + 1];
            o1z += av1 * dirv[(t * KNN + k) * 3 + 2];
        }
    }
    out0[(size_t)t * CDIM + c] = o0;
    out1[0 * (size_t)T_NODES * CDIM + (size_t)t * CDIM + c] = o1x;
    out1[1 * (size_t)T_NODES * CDIM + (size_t)t * CDIM + c] = o1y;
    out1[2 * (size_t)T_NODES * CDIM + (size_t)t * CDIM + c] = o1z;
}

// ---------------------------------------------------------------------------
// Kernel 6: f1 = out1 @ Wo1 (per xyz), inv = ||f1||, f0_out = f0 + out0@Wo0 + inv@Wg
// 16 nodes per block, 256 threads (2 halves x 128 channels).
// ---------------------------------------------------------------------------
__global__ __launch_bounds__(256) void k_mix(const float* __restrict__ f0,
                                             const float* __restrict__ out0,
                                             const float* __restrict__ out1,
                                             const float* __restrict__ Wo1,
                                             const float* __restrict__ Wo0,
                                             const float* __restrict__ Wg,
                                             float* __restrict__ f0out) {
    __shared__ float sinv[16][CDIM];
    int t0 = blockIdx.x * 16;
    int d = threadIdx.x & 127;
    int half = threadIdx.x >> 7;  // 0 or 1

    // Phase 1: f1 / inv for nodes nn = half + 2*i
    float a0[8], a1[8], a2[8];
#pragma unroll
    for (int i = 0; i < 8; ++i) { a0[i] = 0.f; a1[i] = 0.f; a2[i] = 0.f; }

    for (int c0 = 0; c0 < CDIM; c0 += 8) {
        float w[8];
#pragma unroll
        for (int cc = 0; cc < 8; ++cc) w[cc] = Wo1[(c0 + cc) * CDIM + d];
#pragma unroll
        for (int i = 0; i < 8; ++i) {
            int t = t0 + half + 2 * i;
#pragma unroll
            for (int cc = 0; cc < 8; ++cc) {
                float wv = w[cc];
                a0[i] += out1[0 * (size_t)T_NODES * CDIM + (size_t)t * CDIM + c0 + cc] * wv;
                a1[i] += out1[1 * (size_t)T_NODES * CDIM + (size_t)t * CDIM + c0 + cc] * wv;
                a2[i] += out1[2 * (size_t)T_NODES * CDIM + (size_t)t * CDIM + c0 + cc] * wv;
            }
        }
    }
#pragma unroll
    for (int i = 0; i < 8; ++i) {
        int nn = half + 2 * i;
        sinv[nn][d] = sqrtf(a0[i] * a0[i] + a1[i] * a1[i] + a2[i] * a2[i] + 1e-6f);
    }
    __syncthreads();

    // Phase 2: f0_out = f0 + out0 @ Wo0 + inv @ Wg
    float r[8];
#pragma unroll
    for (int i = 0; i < 8; ++i) {
        int t = t0 + half + 2 * i;
        r[i] = f0[(size_t)t * CDIM + d];
    }
    for (int c0 = 0; c0 < CDIM; c0 += 8) {
        float wo[8], wg[8];
#pragma unroll
        for (int cc = 0; cc < 8; ++cc) {
            wo[cc] = Wo0[(c0 + cc) * CDIM + d];
            wg[cc] = Wg[(c0 + cc) * CDIM + d];
        }
#pragma unroll
        for (int i = 0; i < 8; ++i) {
            int nn = half + 2 * i;
            int t = t0 + nn;
#pragma unroll
            for (int cc = 0; cc < 8; ++cc) {
                r[i] += out0[(size_t)t * CDIM + c0 + cc] * wo[cc]
                      + sinv[nn][c0 + cc] * wg[cc];
            }
        }
    }
#pragma unroll
    for (int i = 0; i < 8; ++i) {
        int t = t0 + half + 2 * i;
        f0out[(size_t)t * CDIM + d] = r[i];
    }
}

// ---------------------------------------------------------------------------
// Kernel 7: masked mean pool per graph + linear head -> out [B,19]
// One block of 1024 threads per graph: 8 node-slices x 128 channels,
// LDS reduce, then 19 outputs x 32-lane shuffle-reduce head.
// ---------------------------------------------------------------------------
__global__ __launch_bounds__(1024) void k_pool(const float* __restrict__ f0out,
                                               const int* __restrict__ starts,
                                               const int* __restrict__ counts,
                                               const float* __restrict__ headW,
                                               const float* __restrict__ headb,
                                               float* __restrict__ out) {
    __shared__ float part[8][CDIM];
    int b = blockIdx.x;
    int tid = threadIdx.x;
    int c = tid & 127;
    int slice = tid >> 7;  // 0..7
    int s = starts[b];
    int n = counts[b];

    float acc = 0.f;
    for (int i = slice; i < n; i += 8) {
        acc += f0out[(size_t)(s + i) * CDIM + c];
    }
    part[slice][c] = acc;
    __syncthreads();

    if (slice == 0) {
        float v = part[0][c] + part[1][c] + part[2][c] + part[3][c]
                + part[4][c] + part[5][c] + part[6][c] + part[7][c];
        part[0][c] = v / fmaxf((float)n, 1.f);  // pooled mean
    }
    __syncthreads();

    // head: outputs o=0..18, each computed by a 32-lane group.
    if (tid < 19 * 32) {
        int o = tid >> 5;
        int l = tid & 31;
        float p = 0.f;
#pragma unroll
        for (int cc = 0; cc < 4; ++cc) {
            int ch = l + cc * 32;
            p += part[0][ch] * headW[ch * 19 + o];
        }
        p += __shfl_xor(p, 16);
        p += __shfl_xor(p, 8);
        p += __shfl_xor(p, 4);
        p += __shfl_xor(p, 2);
        p += __shfl_xor(p, 1);
        if (l == 0) out[b * 19 + o] = p + headb[o];
    }
}

// ---------------------------------------------------------------------------
extern "C" void kernel_launch(void* const* d_in, const int* in_sizes, int n_in,
                              void* d_out, int out_size, void* d_ws, size_t ws_size,
                              hipStream_t stream) {
    const float* x    = (const float*)d_in[0];   // [T,11]
    const float* pos  = (const float*)d_in[1];   // [T,3]
    const int* batch  = (const int*)d_in[2];     // [T]
    const float* embW = (const float*)d_in[3];   // [11,128]
    const float* embb = (const float*)d_in[4];   // [128]
    const float* Wq   = (const float*)d_in[5];
    const float* Wk   = (const float*)d_in[6];
    const float* Wv0  = (const float*)d_in[7];
    const float* Wv1  = (const float*)d_in[8];
    const float* Wo0  = (const float*)d_in[9];
    const float* Wo1  = (const float*)d_in[10];
    const float* Wg   = (const float*)d_in[11];
    const float* dist_scale = (const float*)d_in[12];  // [4]
    const float* headW = (const float*)d_in[13];       // [128,19]
    const float* headb = (const float*)d_in[14];       // [19]
    float* out = (float*)d_out;                        // [16,19]

    char* w = (char*)d_ws;
    int* counts = (int*)w;
    int* starts = (int*)(w + 64);
    float* f0   = (float*)(w + 256);
    float* qkvv = f0 + (size_t)T_NODES * CDIM;
    int* nbr    = (int*)(qkvv + (size_t)T_NODES * 512);
    float* dist = (float*)(nbr + (size_t)T_NODES * KNN);
    float* dirv = dist + (size_t)T_NODES * KNN;
    float* out0 = dirv + (size_t)T_NODES * KNN * 3;
    float* out1 = out0 + (size_t)T_NODES * CDIM;
    float* f0out = out1 + (size_t)T_NODES * CDIM * 3;

    k_counts<<<1, 256, 0, stream>>>(batch, starts, counts);
    k_embed<<<(T_NODES * CDIM) / 256, 256, 0, stream>>>(x, embW, embb, f0);
    k_knn<<<T_NODES / 4, 256, 0, stream>>>(pos, batch, starts, counts, nbr, dist, dirv);
    k_qkv<<<T_NODES / 16, 256, 0, stream>>>(f0, Wq, Wk, Wv0, Wv1, qkvv);
    k_attn<<<T_NODES, 128, 0, stream>>>(qkvv, nbr, dist, dirv, dist_scale, out0, out1);
    k_mix<<<T_NODES / 16, 256, 0, stream>>>(f0, out0, out1, Wo1, Wo0, Wg, f0out);
    k_pool<<<BGRAPHS, 1024, 0, stream>>>(f0out, starts, counts, headW, headb, out);
}

// Round 4
// 193.193 us; speedup vs baseline: 1.9158x; 1.3042x over previous
//
#include <hip/hip_runtime.h>
#include <hip/hip_bf16.h>
#include <math.h>

#define T_NODES 8192
#define BGRAPHS 16
#define CDIM 128
#define HEADS 4
#define DHEAD 32
#define KNN 16

// ---------------------------------------------------------------------------
// Kernel 1: segment counts/starts from sorted batch ids
// ---------------------------------------------------------------------------
__global__ __launch_bounds__(256) void k_counts(const int* __restrict__ batch,
                                                int* __restrict__ starts,
                                                int* __restrict__ counts) {
    __shared__ int cnt[BGRAPHS];
    int tid = threadIdx.x;
    if (tid < BGRAPHS) cnt[tid] = 0;
    __syncthreads();
    for (int i = tid; i < T_NODES; i += 256) {
        atomicAdd(&cnt[batch[i]], 1);
    }
    __syncthreads();
    if (tid == 0) {
        int s = 0;
        for (int b = 0; b < BGRAPHS; ++b) {
            starts[b] = s;
            counts[b] = cnt[b];
            s += cnt[b];
        }
    }
}

// ---------------------------------------------------------------------------
// Kernel 2: node embedding f0 = x @ emb_W + emb_b   [T,128]
// ---------------------------------------------------------------------------
__global__ __launch_bounds__(256) void k_embed(const float* __restrict__ x,
                                               const float* __restrict__ embW,
                                               const float* __restrict__ embb,
                                               float* __restrict__ f0) {
    int gid = blockIdx.x * 256 + threadIdx.x;
    int t = gid >> 7;
    int c = gid & 127;
    float acc = embb[c];
#pragma unroll
    for (int i = 0; i < 11; ++i) {
        acc += x[t * 11 + i] * embW[i * CDIM + c];
    }
    f0[t * CDIM + c] = acc;
}

// ---------------------------------------------------------------------------
// Kernel 3: kNN. One wave (64 lanes) per node. Each lane holds 16 candidate
// slots (covers up to 1024 nodes/graph). 16 rounds of argmin-reduce.
// Tie-break: smaller index wins (matches jax.lax.top_k).
// ---------------------------------------------------------------------------
__global__ __launch_bounds__(256) void k_knn(const float* __restrict__ pos,
                                             const int* __restrict__ batch,
                                             const int* __restrict__ starts,
                                             const int* __restrict__ counts,
                                             int* __restrict__ nbr,
                                             float* __restrict__ dist,
                                             float* __restrict__ dirv) {
    int wave = threadIdx.x >> 6;
    int lane = threadIdx.x & 63;
    int t = blockIdx.x * 4 + wave;
    if (t >= T_NODES) return;

    int b = batch[t];
    int s = starts[b];
    int n = counts[b];

    float px = pos[t * 3 + 0];
    float py = pos[t * 3 + 1];
    float pz = pos[t * 3 + 2];

    float d2s[16];
#pragma unroll
    for (int sl = 0; sl < 16; ++sl) {
        int j = lane + sl * 64;
        float d2 = 1e30f;
        if (j < n) {
            int jj = s + j;
            float dx = px - pos[jj * 3 + 0];
            float dy = py - pos[jj * 3 + 1];
            float dz = pz - pos[jj * 3 + 2];
            d2 = dx * dx + dy * dy + dz * dz;
        }
        d2s[sl] = d2;
    }

    float resd = 1e30f;
    int resj = -1;

#pragma unroll
    for (int r = 0; r < KNN; ++r) {
        // local argmin over my 16 slots (static indices)
        float bd = 1e30f;
        int bj = 0x7fffffff;
#pragma unroll
        for (int sl = 0; sl < 16; ++sl) {
            int j = lane + sl * 64;
            float d2 = d2s[sl];
            bool take = (d2 < bd) || (d2 == bd && j < bj);
            bd = take ? d2 : bd;
            bj = take ? j : bj;
        }
        // wave argmin reduce (lexicographic (d2, j))
#pragma unroll
        for (int off = 32; off >= 1; off >>= 1) {
            float od = __shfl_xor(bd, off);
            int oj = __shfl_xor(bj, off);
            bool take = (od < bd) || (od == bd && oj < bj);
            bd = take ? od : bd;
            bj = take ? oj : bj;
        }
        // invalidate winner (owning lane only; static slot compare)
#pragma unroll
        for (int sl = 0; sl < 16; ++sl) {
            int j = lane + sl * 64;
            if (j == bj) d2s[sl] = 1e30f;
        }
        if (lane == r) { resd = bd; resj = bj; }
    }

    if (lane < KNN) {
        bool valid = (resd < 1e29f);
        int jf = valid ? (s + resj) : -1;
        nbr[t * KNN + lane] = jf;
        float dd = sqrtf(resd + 1e-6f);
        dist[t * KNN + lane] = dd;
        float dx = 0.f, dy = 0.f, dz = 0.f;
        if (valid) {
            float inv = 1.f / dd;
            dx = (px - pos[jf * 3 + 0]) * inv;
            dy = (py - pos[jf * 3 + 1]) * inv;
            dz = (pz - pos[jf * 3 + 2]) * inv;
        }
        dirv[(t * KNN + lane) * 3 + 0] = dx;
        dirv[(t * KNN + lane) * 3 + 1] = dy;
        dirv[(t * KNN + lane) * 3 + 2] = dz;
    }
}

// ---------------------------------------------------------------------------
// Kernel 4: fused QKV projection. qkvv[t, 0:512] = f0[t,:] @ [Wq|Wk|Wv0|Wv1]
// 16 nodes per block, 256 threads. Thread owns 2 output columns x 16 nodes.
// ---------------------------------------------------------------------------
__global__ __launch_bounds__(256) void k_qkv(const float* __restrict__ f0,
                                             const float* __restrict__ Wq,
                                             const float* __restrict__ Wk,
                                             const float* __restrict__ Wv0,
                                             const float* __restrict__ Wv1,
                                             float* __restrict__ qkvv) {
    __shared__ float sf[16][CDIM];
    int t0 = blockIdx.x * 16;
    int tid = threadIdx.x;
    for (int i = tid; i < 16 * CDIM; i += 256) {
        sf[i >> 7][i & 127] = f0[(t0 + (i >> 7)) * CDIM + (i & 127)];
    }
    __syncthreads();

    const float* W1 = (tid < 128) ? Wq : Wk;    // wave-uniform
    const float* W2 = (tid < 128) ? Wv0 : Wv1;  // wave-uniform
    int col = tid & 127;

    float acc1[16], acc2[16];
#pragma unroll
    for (int nn = 0; nn < 16; ++nn) { acc1[nn] = 0.f; acc2[nn] = 0.f; }

    for (int c0 = 0; c0 < CDIM; c0 += 8) {
        float w1[8], w2[8];
#pragma unroll
        for (int cc = 0; cc < 8; ++cc) {
            w1[cc] = W1[(c0 + cc) * CDIM + col];
            w2[cc] = W2[(c0 + cc) * CDIM + col];
        }
#pragma unroll
        for (int nn = 0; nn < 16; ++nn) {
            float4 fa = *(const float4*)&sf[nn][c0];
            float4 fb = *(const float4*)&sf[nn][c0 + 4];
            acc1[nn] += fa.x * w1[0] + fa.y * w1[1] + fa.z * w1[2] + fa.w * w1[3]
                      + fb.x * w1[4] + fb.y * w1[5] + fb.z * w1[6] + fb.w * w1[7];
            acc2[nn] += fa.x * w2[0] + fa.y * w2[1] + fa.z * w2[2] + fa.w * w2[3]
                      + fb.x * w2[4] + fb.y * w2[5] + fb.z * w2[6] + fb.w * w2[7];
        }
    }
#pragma unroll
    for (int nn = 0; nn < 16; ++nn) {
        qkvv[(size_t)(t0 + nn) * 512 + tid] = acc1[nn];
        qkvv[(size_t)(t0 + nn) * 512 + 256 + tid] = acc2[nn];
    }
}

// ---------------------------------------------------------------------------
// Kernel 5: kNN attention. One block (128 threads = channels) per node.
// out0 [T,128]; out1 planar [3][T,128].
// ---------------------------------------------------------------------------
__global__ __launch_bounds__(128) void k_attn(const float* __restrict__ qkvv,
                                              const int* __restrict__ nbr,
                                              const float* __restrict__ dist,
                                              const float* __restrict__ dirv,
                                              const float* __restrict__ dist_scale,
                                              float* __restrict__ out0,
                                              float* __restrict__ out1) {
    int t = blockIdx.x;
    int c = threadIdx.x;  // 0..127
    int h = c >> 5;

    float q = qkvv[(size_t)t * 512 + c];
    float xs = dist_scale[h];
    float sp = (xs > 20.f) ? xs : log1pf(expf(xs));  // softplus

    int js[KNN];
    float lg[KNN];
#pragma unroll
    for (int k = 0; k < KNN; ++k) {
        int j = nbr[t * KNN + k];
        js[k] = j;
        float kv = (j >= 0) ? qkvv[(size_t)j * 512 + 128 + c] : 0.f;
        float p = q * kv;
        p += __shfl_xor(p, 16);
        p += __shfl_xor(p, 8);
        p += __shfl_xor(p, 4);
        p += __shfl_xor(p, 2);
        p += __shfl_xor(p, 1);
        float l = -1e30f;
        if (j >= 0) l = p * 0.17677669529663687f - sp * dist[t * KNN + k];
        lg[k] = l;
    }

    float m = lg[0];
#pragma unroll
    for (int k = 1; k < KNN; ++k) m = fmaxf(m, lg[k]);
    float ssum = 0.f;
    float at[KNN];
#pragma unroll
    for (int k = 0; k < KNN; ++k) {
        float e = expf(lg[k] - m);
        at[k] = e;
        ssum += e;
    }
    float rs = 1.f / ssum;

    float o0 = 0.f, o1x = 0.f, o1y = 0.f, o1z = 0.f;
#pragma unroll
    for (int k = 0; k < KNN; ++k) {
        int j = js[k];
        if (j >= 0) {
            float a = at[k] * rs;
            float v0 = qkvv[(size_t)j * 512 + 256 + c];
            float v1 = qkvv[(size_t)j * 512 + 384 + c];
            o0 += a * v0;
            float av1 = a * v1;
            o1x += av1 * dirv[(t * KNN + k) * 3 + 0];
            o1y += av1 * dirv[(t * KNN + k) * 3 + 1];
            o1z += av1 * dirv[(t * KNN + k) * 3 + 2];
        }
    }
    out0[(size_t)t * CDIM + c] = o0;
    out1[0 * (size_t)T_NODES * CDIM + (size_t)t * CDIM + c] = o1x;
    out1[1 * (size_t)T_NODES * CDIM + (size_t)t * CDIM + c] = o1y;
    out1[2 * (size_t)T_NODES * CDIM + (size_t)t * CDIM + c] = o1z;
}

// ---------------------------------------------------------------------------
// Kernel 6: f1 = out1 @ Wo1 (per xyz), inv = ||f1||, f0_out = f0 + out0@Wo0 + inv@Wg
// LDS-staged, register-blocked. 8 nodes/block, 256 threads.
// Thread (d0=tid&63, g=tid>>6) computes nodes {g, g+4} x channels {d0, d0+64}.
// LDS reads are wave-broadcast (all 64 lanes same address) -> conflict-free.
// ---------------------------------------------------------------------------
#define MIXN 8
__global__ __launch_bounds__(256) void k_mix(const float* __restrict__ f0,
                                             const float* __restrict__ out0,
                                             const float* __restrict__ out1,
                                             const float* __restrict__ Wo1,
                                             const float* __restrict__ Wo0,
                                             const float* __restrict__ Wg,
                                             float* __restrict__ f0out) {
    __shared__ float s_out1[3][MIXN][CDIM];  // 12 KB
    __shared__ float s_out0[MIXN][CDIM];     //  4 KB
    __shared__ float s_inv[MIXN][CDIM];      //  4 KB
    int tid = threadIdx.x;
    int t0 = blockIdx.x * MIXN;

    // stage out1 (3 x 8 x 128 floats = 768 float4) and out0 (256 float4)
    {
        const float4* p1 = (const float4*)out1;
        float4* s1 = (float4*)s_out1;
        for (int i = tid; i < 3 * MIXN * 32; i += 256) {
            int cp = i >> 8;         // / 256
            int rem = i & 255;
            int nn = rem >> 5;
            int c4 = rem & 31;
            s1[i] = p1[(size_t)cp * (T_NODES * 32) + (size_t)(t0 + nn) * 32 + c4];
        }
        const float4* p0 = (const float4*)out0;
        float4* s0 = (float4*)s_out0;
        {
            int i = tid;  // exactly 256 float4s
            int nn = i >> 5, c4 = i & 31;
            s0[i] = p0[(size_t)(t0 + nn) * 32 + c4];
        }
    }
    __syncthreads();

    int d0 = tid & 63;
    int g = tid >> 6;  // 0..3; nodes g and g+4

    // Phase 1: f1 accumulators [node][comp][dcol]
    float f1a[2][3][2];
#pragma unroll
    for (int ni = 0; ni < 2; ++ni)
#pragma unroll
        for (int cp = 0; cp < 3; ++cp) {
            f1a[ni][cp][0] = 0.f;
            f1a[ni][cp][1] = 0.f;
        }

    for (int c0 = 0; c0 < CDIM; c0 += 4) {
        float w[4][2];
#pragma unroll
        for (int cc = 0; cc < 4; ++cc) {
            w[cc][0] = Wo1[(c0 + cc) * CDIM + d0];
            w[cc][1] = Wo1[(c0 + cc) * CDIM + d0 + 64];
        }
#pragma unroll
        for (int ni = 0; ni < 2; ++ni) {
            int nn = g + ni * 4;
#pragma unroll
            for (int cp = 0; cp < 3; ++cp) {
                float4 v = *(const float4*)&s_out1[cp][nn][c0];
                f1a[ni][cp][0] += v.x * w[0][0] + v.y * w[1][0] + v.z * w[2][0] + v.w * w[3][0];
                f1a[ni][cp][1] += v.x * w[0][1] + v.y * w[1][1] + v.z * w[2][1] + v.w * w[3][1];
            }
        }
    }
#pragma unroll
    for (int ni = 0; ni < 2; ++ni) {
        int nn = g + ni * 4;
        s_inv[nn][d0] = sqrtf(f1a[ni][0][0] * f1a[ni][0][0] + f1a[ni][1][0] * f1a[ni][1][0]
                            + f1a[ni][2][0] * f1a[ni][2][0] + 1e-6f);
        s_inv[nn][d0 + 64] = sqrtf(f1a[ni][0][1] * f1a[ni][0][1] + f1a[ni][1][1] * f1a[ni][1][1]
                                 + f1a[ni][2][1] * f1a[ni][2][1] + 1e-6f);
    }
    __syncthreads();

    // Phase 2: r = f0 + out0 @ Wo0 + inv @ Wg
    float r[2][2];
#pragma unroll
    for (int ni = 0; ni < 2; ++ni) {
        int t = t0 + g + ni * 4;
        r[ni][0] = f0[(size_t)t * CDIM + d0];
        r[ni][1] = f0[(size_t)t * CDIM + d0 + 64];
    }
    for (int c0 = 0; c0 < CDIM; c0 += 4) {
        float wo[4][2], wg[4][2];
#pragma unroll
        for (int cc = 0; cc < 4; ++cc) {
            wo[cc][0] = Wo0[(c0 + cc) * CDIM + d0];
            wo[cc][1] = Wo0[(c0 + cc) * CDIM + d0 + 64];
            wg[cc][0] = Wg[(c0 + cc) * CDIM + d0];
            wg[cc][1] = Wg[(c0 + cc) * CDIM + d0 + 64];
        }
#pragma unroll
        for (int ni = 0; ni < 2; ++ni) {
            int nn = g + ni * 4;
            float4 a = *(const float4*)&s_out0[nn][c0];
            float4 b = *(const float4*)&s_inv[nn][c0];
            r[ni][0] += a.x * wo[0][0] + a.y * wo[1][0] + a.z * wo[2][0] + a.w * wo[3][0]
                      + b.x * wg[0][0] + b.y * wg[1][0] + b.z * wg[2][0] + b.w * wg[3][0];
            r[ni][1] += a.x * wo[0][1] + a.y * wo[1][1] + a.z * wo[2][1] + a.w * wo[3][1]
                      + b.x * wg[0][1] + b.y * wg[1][1] + b.z * wg[2][1] + b.w * wg[3][1];
        }
    }
#pragma unroll
    for (int ni = 0; ni < 2; ++ni) {
        int t = t0 + g + ni * 4;
        f0out[(size_t)t * CDIM + d0] = r[ni][0];
        f0out[(size_t)t * CDIM + d0 + 64] = r[ni][1];
    }
}

// ---------------------------------------------------------------------------
// Kernel 7: masked mean pool per graph + linear head -> out [B,19]
// One block of 1024 threads per graph: 8 node-slices x 128 channels,
// LDS reduce, then 19 outputs x 32-lane shuffle-reduce head.
// ---------------------------------------------------------------------------
__global__ __launch_bounds__(1024) void k_pool(const float* __restrict__ f0out,
                                               const int* __restrict__ starts,
                                               const int* __restrict__ counts,
                                               const float* __restrict__ headW,
                                               const float* __restrict__ headb,
                                               float* __restrict__ out) {
    __shared__ float part[8][CDIM];
    int b = blockIdx.x;
    int tid = threadIdx.x;
    int c = tid & 127;
    int slice = tid >> 7;  // 0..7
    int s = starts[b];
    int n = counts[b];

    float acc = 0.f;
    for (int i = slice; i < n; i += 8) {
        acc += f0out[(size_t)(s + i) * CDIM + c];
    }
    part[slice][c] = acc;
    __syncthreads();

    if (slice == 0) {
        float v = part[0][c] + part[1][c] + part[2][c] + part[3][c]
                + part[4][c] + part[5][c] + part[6][c] + part[7][c];
        part[0][c] = v / fmaxf((float)n, 1.f);  // pooled mean
    }
    __syncthreads();

    // head: outputs o=0..18, each computed by a 32-lane group.
    if (tid < 19 * 32) {
        int o = tid >> 5;
        int l = tid & 31;
        float p = 0.f;
#pragma unroll
        for (int cc = 0; cc < 4; ++cc) {
            int ch = l + cc * 32;
            p += part[0][ch] * headW[ch * 19 + o];
        }
        p += __shfl_xor(p, 16);
        p += __shfl_xor(p, 8);
        p += __shfl_xor(p, 4);
        p += __shfl_xor(p, 2);
        p += __shfl_xor(p, 1);
        if (l == 0) out[b * 19 + o] = p + headb[o];
    }
}

// ---------------------------------------------------------------------------
extern "C" void kernel_launch(void* const* d_in, const int* in_sizes, int n_in,
                              void* d_out, int out_size, void* d_ws, size_t ws_size,
                              hipStream_t stream) {
    const float* x    = (const float*)d_in[0];   // [T,11]
    const float* pos  = (const float*)d_in[1];   // [T,3]
    const int* batch  = (const int*)d_in[2];     // [T]
    const float* embW = (const float*)d_in[3];   // [11,128]
    const float* embb = (const float*)d_in[4];   // [128]
    const float* Wq   = (const float*)d_in[5];
    const float* Wk   = (const float*)d_in[6];
    const float* Wv0  = (const float*)d_in[7];
    const float* Wv1  = (const float*)d_in[8];
    const float* Wo0  = (const float*)d_in[9];
    const float* Wo1  = (const float*)d_in[10];
    const float* Wg   = (const float*)d_in[11];
    const float* dist_scale = (const float*)d_in[12];  // [4]
    const float* headW = (const float*)d_in[13];       // [128,19]
    const float* headb = (const float*)d_in[14];       // [19]
    float* out = (float*)d_out;                        // [16,19]

    char* w = (char*)d_ws;
    int* counts = (int*)w;
    int* starts = (int*)(w + 64);
    float* f0   = (float*)(w + 256);
    float* qkvv = f0 + (size_t)T_NODES * CDIM;
    int* nbr    = (int*)(qkvv + (size_t)T_NODES * 512);
    float* dist = (float*)(nbr + (size_t)T_NODES * KNN);
    float* dirv = dist + (size_t)T_NODES * KNN;
    float* out0 = dirv + (size_t)T_NODES * KNN * 3;
    float* out1 = out0 + (size_t)T_NODES * CDIM;
    float* f0out = out1 + (size_t)T_NODES * CDIM * 3;

    k_counts<<<1, 256, 0, stream>>>(batch, starts, counts);
    k_embed<<<(T_NODES * CDIM) / 256, 256, 0, stream>>>(x, embW, embb, f0);
    k_knn<<<T_NODES / 4, 256, 0, stream>>>(pos, batch, starts, counts, nbr, dist, dirv);
    k_qkv<<<T_NODES / 16, 256, 0, stream>>>(f0, Wq, Wk, Wv0, Wv1, qkvv);
    k_attn<<<T_NODES, 128, 0, stream>>>(qkvv, nbr, dist, dirv, dist_scale, out0, out1);
    k_mix<<<T_NODES / MIXN, 256, 0, stream>>>(f0, out0, out1, Wo1, Wo0, Wg, f0out);
    k_pool<<<BGRAPHS, 1024, 0, stream>>>(f0out, starts, counts, headW, headb, out);
}

// Round 5
// 164.783 us; speedup vs baseline: 2.2461x; 1.1724x over previous
//
#include <hip/hip_runtime.h>
#include <hip/hip_bf16.h>
#include <math.h>

#define T_NODES 8192
#define BGRAPHS 16
#define CDIM 128
#define HEADS 4
#define DHEAD 32
#define KNN 16

// ---------------------------------------------------------------------------
// Kernel 1: segment counts/starts from sorted batch ids
// ---------------------------------------------------------------------------
__global__ __launch_bounds__(256) void k_counts(const int* __restrict__ batch,
                                                int* __restrict__ starts,
                                                int* __restrict__ counts) {
    __shared__ int cnt[BGRAPHS];
    int tid = threadIdx.x;
    if (tid < BGRAPHS) cnt[tid] = 0;
    __syncthreads();
    for (int i = tid; i < T_NODES; i += 256) {
        atomicAdd(&cnt[batch[i]], 1);
    }
    __syncthreads();
    if (tid == 0) {
        int s = 0;
        for (int b = 0; b < BGRAPHS; ++b) {
            starts[b] = s;
            counts[b] = cnt[b];
            s += cnt[b];
        }
    }
}

// ---------------------------------------------------------------------------
// Kernel 2: node embedding f0 = x @ emb_W + emb_b   [T,128]
// ---------------------------------------------------------------------------
__global__ __launch_bounds__(256) void k_embed(const float* __restrict__ x,
                                               const float* __restrict__ embW,
                                               const float* __restrict__ embb,
                                               float* __restrict__ f0) {
    int gid = blockIdx.x * 256 + threadIdx.x;
    int t = gid >> 7;
    int c = gid & 127;
    float acc = embb[c];
#pragma unroll
    for (int i = 0; i < 11; ++i) {
        acc += x[t * 11 + i] * embW[i * CDIM + c];
    }
    f0[t * CDIM + c] = acc;
}

// ---------------------------------------------------------------------------
// Kernel 3: kNN. One wave (64 lanes) per node; lane holds 16 candidate slots
// (j = lane + sl*64, coalesced). Each lane Batcher-sorts its 16 (d2, slot)
// pairs once; then 16 rounds of {d2-only fmin wave reduce -> ballot winner ->
// winner shifts}. Tie-break arbitrary (output is neighbor-set invariant;
// exact float d2 ties have measure ~0 on continuous coords).
// ---------------------------------------------------------------------------
__global__ __launch_bounds__(256) void k_knn(const float* __restrict__ pos,
                                             const int* __restrict__ batch,
                                             const int* __restrict__ starts,
                                             const int* __restrict__ counts,
                                             int* __restrict__ nbr,
                                             float* __restrict__ dist,
                                             float* __restrict__ dirv) {
    int wave = threadIdx.x >> 6;
    int lane = threadIdx.x & 63;
    int t = blockIdx.x * 4 + wave;
    if (t >= T_NODES) return;

    int b = batch[t];
    int s = starts[b];
    int n = counts[b];

    float px = pos[t * 3 + 0];
    float py = pos[t * 3 + 1];
    float pz = pos[t * 3 + 2];

    float sd[16];
    int ss[16];
#pragma unroll
    for (int sl = 0; sl < 16; ++sl) {
        int j = lane + sl * 64;
        float d2 = 1e30f;
        if (j < n) {
            int jj = s + j;
            float dx = px - pos[jj * 3 + 0];
            float dy = py - pos[jj * 3 + 1];
            float dz = pz - pos[jj * 3 + 2];
            d2 = dx * dx + dy * dy + dz * dz;
        }
        sd[sl] = d2;
        ss[sl] = sl;
    }

    // Batcher odd-even mergesort of 16 (d2, slot) pairs; ascending d2.
#pragma unroll
    for (int p = 1; p < 16; p <<= 1) {
#pragma unroll
        for (int k = p; k >= 1; k >>= 1) {
#pragma unroll
            for (int j = (k & (p - 1)); j + k < 16; j += 2 * k) {
#pragma unroll
                for (int i = 0; i < k; ++i) {
                    if (i + j + k < 16 && ((i + j) / (2 * p)) == ((i + j + k) / (2 * p))) {
                        int a = i + j, c2 = i + j + k;
                        bool sw = sd[a] > sd[c2];
                        float td = sd[a];
                        int ts = ss[a];
                        sd[a] = sw ? sd[c2] : sd[a];
                        ss[a] = sw ? ss[c2] : ss[a];
                        sd[c2] = sw ? td : sd[c2];
                        ss[c2] = sw ? ts : ss[c2];
                    }
                }
            }
        }
    }

    float resd = 1e30f;
    int resj = -1;

#pragma unroll
    for (int r = 0; r < KNN; ++r) {
        // wave min over lane heads (d2 only)
        float rd = sd[0];
#pragma unroll
        for (int off = 32; off >= 1; off >>= 1) {
            rd = fminf(rd, __shfl_xor(rd, off));
        }
        // first lane achieving the min wins
        unsigned long long mask = __ballot(sd[0] == rd);
        int wl = (int)__builtin_ctzll(mask);
        int ws = __shfl(ss[0], wl);
        if (lane == r) { resd = rd; resj = wl + ws * 64; }
        // winner consumes its head
        if (lane == wl) {
#pragma unroll
            for (int i = 0; i < 15; ++i) { sd[i] = sd[i + 1]; ss[i] = ss[i + 1]; }
            sd[15] = 1e30f;
        }
    }

    if (lane < KNN) {
        bool valid = (resd < 1e29f);
        int jf = valid ? (s + resj) : -1;
        nbr[t * KNN + lane] = jf;
        float dd = sqrtf(resd + 1e-6f);
        dist[t * KNN + lane] = dd;
        float dx = 0.f, dy = 0.f, dz = 0.f;
        if (valid) {
            float inv = 1.f / dd;
            dx = (px - pos[jf * 3 + 0]) * inv;
            dy = (py - pos[jf * 3 + 1]) * inv;
            dz = (pz - pos[jf * 3 + 2]) * inv;
        }
        dirv[(t * KNN + lane) * 3 + 0] = dx;
        dirv[(t * KNN + lane) * 3 + 1] = dy;
        dirv[(t * KNN + lane) * 3 + 2] = dz;
    }
}

// ---------------------------------------------------------------------------
// Kernel 4: fused QKV projection. qkvv[t, 0:512] = f0[t,:] @ [Wq|Wk|Wv0|Wv1]
// 16 nodes per block, 256 threads. Thread owns 2 output columns x 16 nodes.
// ---------------------------------------------------------------------------
__global__ __launch_bounds__(256) void k_qkv(const float* __restrict__ f0,
                                             const float* __restrict__ Wq,
                                             const float* __restrict__ Wk,
                                             const float* __restrict__ Wv0,
                                             const float* __restrict__ Wv1,
                                             float* __restrict__ qkvv) {
    __shared__ float sf[16][CDIM];
    int t0 = blockIdx.x * 16;
    int tid = threadIdx.x;
    for (int i = tid; i < 16 * CDIM; i += 256) {
        sf[i >> 7][i & 127] = f0[(t0 + (i >> 7)) * CDIM + (i & 127)];
    }
    __syncthreads();

    const float* W1 = (tid < 128) ? Wq : Wk;    // wave-uniform
    const float* W2 = (tid < 128) ? Wv0 : Wv1;  // wave-uniform
    int col = tid & 127;

    float acc1[16], acc2[16];
#pragma unroll
    for (int nn = 0; nn < 16; ++nn) { acc1[nn] = 0.f; acc2[nn] = 0.f; }

    for (int c0 = 0; c0 < CDIM; c0 += 8) {
        float w1[8], w2[8];
#pragma unroll
        for (int cc = 0; cc < 8; ++cc) {
            w1[cc] = W1[(c0 + cc) * CDIM + col];
            w2[cc] = W2[(c0 + cc) * CDIM + col];
        }
#pragma unroll
        for (int nn = 0; nn < 16; ++nn) {
            float4 fa = *(const float4*)&sf[nn][c0];
            float4 fb = *(const float4*)&sf[nn][c0 + 4];
            acc1[nn] += fa.x * w1[0] + fa.y * w1[1] + fa.z * w1[2] + fa.w * w1[3]
                      + fb.x * w1[4] + fb.y * w1[5] + fb.z * w1[6] + fb.w * w1[7];
            acc2[nn] += fa.x * w2[0] + fa.y * w2[1] + fa.z * w2[2] + fa.w * w2[3]
                      + fb.x * w2[4] + fb.y * w2[5] + fb.z * w2[6] + fb.w * w2[7];
        }
    }
#pragma unroll
    for (int nn = 0; nn < 16; ++nn) {
        qkvv[(size_t)(t0 + nn) * 512 + tid] = acc1[nn];
        qkvv[(size_t)(t0 + nn) * 512 + 256 + tid] = acc2[nn];
    }
}

// ---------------------------------------------------------------------------
// Kernel 5: kNN attention. One block (128 threads = channels) per node.
// out0 [T,128]; out1 planar [3][T,128].
// ---------------------------------------------------------------------------
__global__ __launch_bounds__(128) void k_attn(const float* __restrict__ qkvv,
                                              const int* __restrict__ nbr,
                                              const float* __restrict__ dist,
                                              const float* __restrict__ dirv,
                                              const float* __restrict__ dist_scale,
                                              float* __restrict__ out0,
                                              float* __restrict__ out1) {
    int t = blockIdx.x;
    int c = threadIdx.x;  // 0..127
    int h = c >> 5;

    float q = qkvv[(size_t)t * 512 + c];
    float xs = dist_scale[h];
    float sp = (xs > 20.f) ? xs : log1pf(expf(xs));  // softplus

    int js[KNN];
    float lg[KNN];
#pragma unroll
    for (int k = 0; k < KNN; ++k) {
        int j = nbr[t * KNN + k];
        js[k] = j;
        float kv = (j >= 0) ? qkvv[(size_t)j * 512 + 128 + c] : 0.f;
        float p = q * kv;
        p += __shfl_xor(p, 16);
        p += __shfl_xor(p, 8);
        p += __shfl_xor(p, 4);
        p += __shfl_xor(p, 2);
        p += __shfl_xor(p, 1);
        float l = -1e30f;
        if (j >= 0) l = p * 0.17677669529663687f - sp * dist[t * KNN + k];
        lg[k] = l;
    }

    float m = lg[0];
#pragma unroll
    for (int k = 1; k < KNN; ++k) m = fmaxf(m, lg[k]);
    float ssum = 0.f;
    float at[KNN];
#pragma unroll
    for (int k = 0; k < KNN; ++k) {
        float e = expf(lg[k] - m);
        at[k] = e;
        ssum += e;
    }
    float rs = 1.f / ssum;

    float o0 = 0.f, o1x = 0.f, o1y = 0.f, o1z = 0.f;
#pragma unroll
    for (int k = 0; k < KNN; ++k) {
        int j = js[k];
        if (j >= 0) {
            float a = at[k] * rs;
            float v0 = qkvv[(size_t)j * 512 + 256 + c];
            float v1 = qkvv[(size_t)j * 512 + 384 + c];
            o0 += a * v0;
            float av1 = a * v1;
            o1x += av1 * dirv[(t * KNN + k) * 3 + 0];
            o1y += av1 * dirv[(t * KNN + k) * 3 + 1];
            o1z += av1 * dirv[(t * KNN + k) * 3 + 2];
        }
    }
    out0[(size_t)t * CDIM + c] = o0;
    out1[0 * (size_t)T_NODES * CDIM + (size_t)t * CDIM + c] = o1x;
    out1[1 * (size_t)T_NODES * CDIM + (size_t)t * CDIM + c] = o1y;
    out1[2 * (size_t)T_NODES * CDIM + (size_t)t * CDIM + c] = o1z;
}

// ---------------------------------------------------------------------------
// Kernel 6: f1 = out1 @ Wo1 (per xyz), inv = ||f1||, f0_out = f0 + out0@Wo0 + inv@Wg
// LDS-staged, register-blocked. 8 nodes/block, 256 threads.
// ---------------------------------------------------------------------------
#define MIXN 8
__global__ __launch_bounds__(256) void k_mix(const float* __restrict__ f0,
                                             const float* __restrict__ out0,
                                             const float* __restrict__ out1,
                                             const float* __restrict__ Wo1,
                                             const float* __restrict__ Wo0,
                                             const float* __restrict__ Wg,
                                             float* __restrict__ f0out) {
    __shared__ float s_out1[3][MIXN][CDIM];  // 12 KB
    __shared__ float s_out0[MIXN][CDIM];     //  4 KB
    __shared__ float s_inv[MIXN][CDIM];      //  4 KB
    int tid = threadIdx.x;
    int t0 = blockIdx.x * MIXN;

    {
        const float4* p1 = (const float4*)out1;
        float4* s1 = (float4*)s_out1;
        for (int i = tid; i < 3 * MIXN * 32; i += 256) {
            int cp = i >> 8;
            int rem = i & 255;
            int nn = rem >> 5;
            int c4 = rem & 31;
            s1[i] = p1[(size_t)cp * (T_NODES * 32) + (size_t)(t0 + nn) * 32 + c4];
        }
        const float4* p0 = (const float4*)out0;
        float4* s0 = (float4*)s_out0;
        {
            int i = tid;
            int nn = i >> 5, c4 = i & 31;
            s0[i] = p0[(size_t)(t0 + nn) * 32 + c4];
        }
    }
    __syncthreads();

    int d0 = tid & 63;
    int g = tid >> 6;  // 0..3; nodes g and g+4

    float f1a[2][3][2];
#pragma unroll
    for (int ni = 0; ni < 2; ++ni)
#pragma unroll
        for (int cp = 0; cp < 3; ++cp) {
            f1a[ni][cp][0] = 0.f;
            f1a[ni][cp][1] = 0.f;
        }

    for (int c0 = 0; c0 < CDIM; c0 += 4) {
        float w[4][2];
#pragma unroll
        for (int cc = 0; cc < 4; ++cc) {
            w[cc][0] = Wo1[(c0 + cc) * CDIM + d0];
            w[cc][1] = Wo1[(c0 + cc) * CDIM + d0 + 64];
        }
#pragma unroll
        for (int ni = 0; ni < 2; ++ni) {
            int nn = g + ni * 4;
#pragma unroll
            for (int cp = 0; cp < 3; ++cp) {
                float4 v = *(const float4*)&s_out1[cp][nn][c0];
                f1a[ni][cp][0] += v.x * w[0][0] + v.y * w[1][0] + v.z * w[2][0] + v.w * w[3][0];
                f1a[ni][cp][1] += v.x * w[0][1] + v.y * w[1][1] + v.z * w[2][1] + v.w * w[3][1];
            }
        }
    }
#pragma unroll
    for (int ni = 0; ni < 2; ++ni) {
        int nn = g + ni * 4;
        s_inv[nn][d0] = sqrtf(f1a[ni][0][0] * f1a[ni][0][0] + f1a[ni][1][0] * f1a[ni][1][0]
                            + f1a[ni][2][0] * f1a[ni][2][0] + 1e-6f);
        s_inv[nn][d0 + 64] = sqrtf(f1a[ni][0][1] * f1a[ni][0][1] + f1a[ni][1][1] * f1a[ni][1][1]
                                 + f1a[ni][2][1] * f1a[ni][2][1] + 1e-6f);
    }
    __syncthreads();

    float r[2][2];
#pragma unroll
    for (int ni = 0; ni < 2; ++ni) {
        int t = t0 + g + ni * 4;
        r[ni][0] = f0[(size_t)t * CDIM + d0];
        r[ni][1] = f0[(size_t)t * CDIM + d0 + 64];
    }
    for (int c0 = 0; c0 < CDIM; c0 += 4) {
        float wo[4][2], wg[4][2];
#pragma unroll
        for (int cc = 0; cc < 4; ++cc) {
            wo[cc][0] = Wo0[(c0 + cc) * CDIM + d0];
            wo[cc][1] = Wo0[(c0 + cc) * CDIM + d0 + 64];
            wg[cc][0] = Wg[(c0 + cc) * CDIM + d0];
            wg[cc][1] = Wg[(c0 + cc) * CDIM + d0 + 64];
        }
#pragma unroll
        for (int ni = 0; ni < 2; ++ni) {
            int nn = g + ni * 4;
            float4 a = *(const float4*)&s_out0[nn][c0];
            float4 b2 = *(const float4*)&s_inv[nn][c0];
            r[ni][0] += a.x * wo[0][0] + a.y * wo[1][0] + a.z * wo[2][0] + a.w * wo[3][0]
                      + b2.x * wg[0][0] + b2.y * wg[1][0] + b2.z * wg[2][0] + b2.w * wg[3][0];
            r[ni][1] += a.x * wo[0][1] + a.y * wo[1][1] + a.z * wo[2][1] + a.w * wo[3][1]
                      + b2.x * wg[0][1] + b2.y * wg[1][1] + b2.z * wg[2][1] + b2.w * wg[3][1];
        }
    }
#pragma unroll
    for (int ni = 0; ni < 2; ++ni) {
        int t = t0 + g + ni * 4;
        f0out[(size_t)t * CDIM + d0] = r[ni][0];
        f0out[(size_t)t * CDIM + d0 + 64] = r[ni][1];
    }
}

// ---------------------------------------------------------------------------
// Kernel 7: masked mean pool per graph + linear head -> out [B,19]
// ---------------------------------------------------------------------------
__global__ __launch_bounds__(1024) void k_pool(const float* __restrict__ f0out,
                                               const int* __restrict__ starts,
                                               const int* __restrict__ counts,
                                               const float* __restrict__ headW,
                                               const float* __restrict__ headb,
                                               float* __restrict__ out) {
    __shared__ float part[8][CDIM];
    int b = blockIdx.x;
    int tid = threadIdx.x;
    int c = tid & 127;
    int slice = tid >> 7;  // 0..7
    int s = starts[b];
    int n = counts[b];

    float acc = 0.f;
    for (int i = slice; i < n; i += 8) {
        acc += f0out[(size_t)(s + i) * CDIM + c];
    }
    part[slice][c] = acc;
    __syncthreads();

    if (slice == 0) {
        float v = part[0][c] + part[1][c] + part[2][c] + part[3][c]
                + part[4][c] + part[5][c] + part[6][c] + part[7][c];
        part[0][c] = v / fmaxf((float)n, 1.f);  // pooled mean
    }
    __syncthreads();

    if (tid < 19 * 32) {
        int o = tid >> 5;
        int l = tid & 31;
        float p = 0.f;
#pragma unroll
        for (int cc = 0; cc < 4; ++cc) {
            int ch = l + cc * 32;
            p += part[0][ch] * headW[ch * 19 + o];
        }
        p += __shfl_xor(p, 16);
        p += __shfl_xor(p, 8);
        p += __shfl_xor(p, 4);
        p += __shfl_xor(p, 2);
        p += __shfl_xor(p, 1);
        if (l == 0) out[b * 19 + o] = p + headb[o];
    }
}

// ---------------------------------------------------------------------------
extern "C" void kernel_launch(void* const* d_in, const int* in_sizes, int n_in,
                              void* d_out, int out_size, void* d_ws, size_t ws_size,
                              hipStream_t stream) {
    const float* x    = (const float*)d_in[0];   // [T,11]
    const float* pos  = (const float*)d_in[1];   // [T,3]
    const int* batch  = (const int*)d_in[2];     // [T]
    const float* embW = (const float*)d_in[3];   // [11,128]
    const float* embb = (const float*)d_in[4];   // [128]
    const float* Wq   = (const float*)d_in[5];
    const float* Wk   = (const float*)d_in[6];
    const float* Wv0  = (const float*)d_in[7];
    const float* Wv1  = (const float*)d_in[8];
    const float* Wo0  = (const float*)d_in[9];
    const float* Wo1  = (const float*)d_in[10];
    const float* Wg   = (const float*)d_in[11];
    const float* dist_scale = (const float*)d_in[12];  // [4]
    const float* headW = (const float*)d_in[13];       // [128,19]
    const float* headb = (const float*)d_in[14];       // [19]
    float* out = (float*)d_out;                        // [16,19]

    char* w = (char*)d_ws;
    int* counts = (int*)w;
    int* starts = (int*)(w + 64);
    float* f0   = (float*)(w + 256);
    float* qkvv = f0 + (size_t)T_NODES * CDIM;
    int* nbr    = (int*)(qkvv + (size_t)T_NODES * 512);
    float* dist = (float*)(nbr + (size_t)T_NODES * KNN);
    float* dirv = dist + (size_t)T_NODES * KNN;
    float* out0 = dirv + (size_t)T_NODES * KNN * 3;
    float* out1 = out0 + (size_t)T_NODES * CDIM;
    float* f0out = out1 + (size_t)T_NODES * CDIM * 3;

    k_counts<<<1, 256, 0, stream>>>(batch, starts, counts);
    k_embed<<<(T_NODES * CDIM) / 256, 256, 0, stream>>>(x, embW, embb, f0);
    k_knn<<<T_NODES / 4, 256, 0, stream>>>(pos, batch, starts, counts, nbr, dist, dirv);
    k_qkv<<<T_NODES / 16, 256, 0, stream>>>(f0, Wq, Wk, Wv0, Wv1, qkvv);
    k_attn<<<T_NODES, 128, 0, stream>>>(qkvv, nbr, dist, dirv, dist_scale, out0, out1);
    k_mix<<<T_NODES / MIXN, 256, 0, stream>>>(f0, out0, out1, Wo1, Wo0, Wg, f0out);
    k_pool<<<BGRAPHS, 1024, 0, stream>>>(f0out, starts, counts, headW, headb, out);
}